// Round 1
// baseline (9014.129 us; speedup 1.0000x reference)
//
#include <hip/hip_runtime.h>
#include <math.h>

#define B_   2048
#define DIN_ 512
#define E_   256
#define H_   512
#define V_   1000
#define L_   64

// ---------------------------------------------------------------------------
// Generic fp32 GEMM: Y[m*ldY + yBase + n] = dot(X[m,0:K], W[n,0:K]) + bias[n]
// X: [M x K] row-major, W: [N x K] row-major (i.e. computes X @ W^T + b).
// Tile 64x64, 256 threads, 4x4 micro-tile. M assumed multiple of 64, K mult of 16.
// ---------------------------------------------------------------------------
__global__ __launch_bounds__(256) void gemm_xwt(
    const float* __restrict__ X, const float* __restrict__ W,
    const float* __restrict__ bias, float* __restrict__ Y,
    int N, int K, long ldY, long yBase)
{
    __shared__ float As[16][68];   // [k][m], pad to 68 keeps float4 alignment
    __shared__ float Bs[16][68];   // [k][n]

    const int tid = threadIdx.x;
    const int tx = tid & 15;       // n-group
    const int ty = tid >> 4;       // m-group
    const int m0 = blockIdx.x * 64;
    const int n0 = blockIdx.y * 64;
    const int lrow = tid >> 2;           // 0..63
    const int lk   = (tid & 3) * 4;      // 0,4,8,12

    float acc[4][4];
#pragma unroll
    for (int i = 0; i < 4; ++i)
#pragma unroll
        for (int j = 0; j < 4; ++j) acc[i][j] = 0.f;

    for (int k0 = 0; k0 < K; k0 += 16) {
        const float4 xa = *reinterpret_cast<const float4*>(&X[(long)(m0 + lrow) * K + k0 + lk]);
        float4 wb;
        const int wrow = n0 + lrow;
        if (wrow < N) {
            wb = *reinterpret_cast<const float4*>(&W[(long)wrow * K + k0 + lk]);
        } else {
            wb.x = wb.y = wb.z = wb.w = 0.f;
        }
        As[lk + 0][lrow] = xa.x; As[lk + 1][lrow] = xa.y;
        As[lk + 2][lrow] = xa.z; As[lk + 3][lrow] = xa.w;
        Bs[lk + 0][lrow] = wb.x; Bs[lk + 1][lrow] = wb.y;
        Bs[lk + 2][lrow] = wb.z; Bs[lk + 3][lrow] = wb.w;
        __syncthreads();

#pragma unroll
        for (int k = 0; k < 16; ++k) {
            const float4 a = *reinterpret_cast<const float4*>(&As[k][ty * 4]);
            const float4 b = *reinterpret_cast<const float4*>(&Bs[k][tx * 4]);
            acc[0][0] += a.x * b.x; acc[0][1] += a.x * b.y; acc[0][2] += a.x * b.z; acc[0][3] += a.x * b.w;
            acc[1][0] += a.y * b.x; acc[1][1] += a.y * b.y; acc[1][2] += a.y * b.z; acc[1][3] += a.y * b.w;
            acc[2][0] += a.z * b.x; acc[2][1] += a.z * b.y; acc[2][2] += a.z * b.z; acc[2][3] += a.z * b.w;
            acc[3][0] += a.w * b.x; acc[3][1] += a.w * b.y; acc[3][2] += a.w * b.z; acc[3][3] += a.w * b.w;
        }
        __syncthreads();
    }

#pragma unroll
    for (int i = 0; i < 4; ++i) {
        const int m = m0 + ty * 4 + i;
#pragma unroll
        for (int j = 0; j < 4; ++j) {
            const int n = n0 + tx * 4 + j;
            if (n < N) Y[(long)m * ldY + yBase + n] = acc[i][j] + bias[n];
        }
    }
}

// ---------------------------------------------------------------------------
// GRU elementwise: PyTorch GRUCell gate order (r,z,n)
// ---------------------------------------------------------------------------
__global__ __launch_bounds__(256) void gru_elem(
    const float* __restrict__ Gi, const float* __restrict__ Gh,
    const float* __restrict__ hin, float* __restrict__ hout)
{
    const long idx = (long)blockIdx.x * 256 + threadIdx.x;  // b*H + j
    const long b = idx >> 9;
    const long j = idx & 511;
    const long base = b * (3 * H_);
    const float gir = Gi[base + j];
    const float giz = Gi[base + H_ + j];
    const float gin = Gi[base + 2 * H_ + j];
    const float ghr = Gh[base + j];
    const float ghz = Gh[base + H_ + j];
    const float ghn = Gh[base + 2 * H_ + j];
    const float r = 1.f / (1.f + expf(-(gir + ghr)));
    const float z = 1.f / (1.f + expf(-(giz + ghz)));
    const float n = tanhf(gin + r * ghn);
    const float h = hin[idx];
    hout[idx] = (1.f - z) * n + z * h;
}

// ---------------------------------------------------------------------------
// Per-row argmax over V=1000 logits (first-index tie-break, like jnp.argmax),
// write token (as float), gather embedding row into i-buffer.
// One block per batch row, 256 threads.
// ---------------------------------------------------------------------------
__global__ __launch_bounds__(256) void argmax_embed(
    const float* __restrict__ logitsBase,   // + b*(L*V) per row (t offset pre-applied)
    float* __restrict__ tokens,             // out base; write tokens[b*L + t]
    const float* __restrict__ embed,        // [V, E]
    float* __restrict__ iB,                 // [B, E]
    int t)
{
    const int b = blockIdx.x;
    const float* row = logitsBase + (long)b * ((long)L_ * V_);
    const int tid = threadIdx.x;

    float best = row[tid];   // tid < 256 <= V always valid
    int   bi   = tid;
    for (int v = tid + 256; v < V_; v += 256) {
        const float x = row[v];
        if (x > best || (x == best && v < bi)) { best = x; bi = v; }
    }
    // wave (64-lane) reduction
#pragma unroll
    for (int off = 32; off > 0; off >>= 1) {
        const float ob = __shfl_down(best, off);
        const int   oi = __shfl_down(bi, off);
        if (ob > best || (ob == best && oi < bi)) { best = ob; bi = oi; }
    }
    __shared__ float sv[4];
    __shared__ int   si[4];
    const int w = tid >> 6;
    if ((tid & 63) == 0) { sv[w] = best; si[w] = bi; }
    __syncthreads();
    __shared__ int finalIdx;
    if (tid == 0) {
        float bb = sv[0]; int ii = si[0];
        for (int q = 1; q < 4; ++q) {
            if (sv[q] > bb || (sv[q] == bb && si[q] < ii)) { bb = sv[q]; ii = si[q]; }
        }
        finalIdx = ii;
        tokens[(long)b * L_ + t] = (float)ii;
    }
    __syncthreads();
    const int fi = finalIdx;
    iB[(long)b * E_ + tid] = embed[(long)fi * E_ + tid];  // E_ == 256 == blockDim
}

// ---------------------------------------------------------------------------
__global__ __launch_bounds__(256) void init_i(
    const float* __restrict__ sos, float* __restrict__ iB)
{
    const long idx = (long)blockIdx.x * 256 + threadIdx.x;  // b*E + e
    iB[idx] = sos[idx & (E_ - 1)];
}

// ---------------------------------------------------------------------------
extern "C" void kernel_launch(void* const* d_in, const int* in_sizes, int n_in,
                              void* d_out, int out_size, void* d_ws, size_t ws_size,
                              hipStream_t stream)
{
    (void)in_sizes; (void)n_in; (void)out_size; (void)ws_size;

    const float* x     = (const float*)d_in[0];
    const float* sos   = (const float*)d_in[1];
    const float* embed = (const float*)d_in[2];
    const float* preW  = (const float*)d_in[3];
    const float* preB  = (const float*)d_in[4];
    const float* Wih   = (const float*)d_in[5];
    const float* Whh   = (const float*)d_in[6];
    const float* bih   = (const float*)d_in[7];
    const float* bhh   = (const float*)d_in[8];
    const float* proW  = (const float*)d_in[9];
    const float* proB  = (const float*)d_in[10];

    float* out    = (float*)d_out;
    float* tokens = out;                          // [B, L] as float values
    float* logits = out + (long)B_ * L_;          // [B, L, V]

    float* hA = (float*)d_ws;                     // [B, H]
    float* hB = hA + (long)B_ * H_;               // [B, H]
    float* iB = hB + (long)B_ * H_;               // [B, E]
    float* Gi = iB + (long)B_ * E_;               // [B, 3H]
    float* Gh = Gi + (long)B_ * 3 * H_;           // [B, 3H]

    const dim3 blk(256);

    // h0 = x @ pre_W^T + pre_b
    gemm_xwt<<<dim3(B_ / 64, H_ / 64), blk, 0, stream>>>(x, preW, preB, hA, H_, DIN_, H_, 0);
    // i0 = broadcast(sos)
    init_i<<<dim3((B_ * E_) / 256), blk, 0, stream>>>(sos, iB);

    float* hin = hA;
    float* hout = hB;
    for (int t = 0; t < L_; ++t) {
        // gi = i @ W_ih^T + b_ih   [B, 3H], K=E
        gemm_xwt<<<dim3(B_ / 64, (3 * H_) / 64), blk, 0, stream>>>(iB, Wih, bih, Gi, 3 * H_, E_, 3 * H_, 0);
        // gh = h @ W_hh^T + b_hh   [B, 3H], K=H
        gemm_xwt<<<dim3(B_ / 64, (3 * H_) / 64), blk, 0, stream>>>(hin, Whh, bhh, Gh, 3 * H_, H_, 3 * H_, 0);
        // h' = GRU(gi, gh, h)
        gru_elem<<<dim3((B_ * H_) / 256), blk, 0, stream>>>(Gi, Gh, hin, hout);
        // logits_t = h' @ pro_W^T + pro_b  -> strided into d_out [B, L, V]
        gemm_xwt<<<dim3(B_ / 64, (V_ + 63) / 64), blk, 0, stream>>>(
            hout, proW, proB, logits, V_, H_, (long)L_ * V_, (long)t * V_);
        // tok = argmax(logits_t); i = embed[tok]
        argmax_embed<<<dim3(B_), blk, 0, stream>>>(logits + (long)t * V_, tokens, embed, iB, t);

        float* tmp = hin; hin = hout; hout = tmp;
    }
}